// Round 9
// baseline (517.345 us; speedup 1.0000x reference)
//
#include <hip/hip_runtime.h>
#include <hip/hip_bf16.h>

typedef _Float16 half8 __attribute__((ext_vector_type(8)));
typedef short short8 __attribute__((ext_vector_type(8)));
typedef short short4v __attribute__((ext_vector_type(4)));
typedef float f32x4 __attribute__((ext_vector_type(4)));

#define BATCH 16
#define SEQ   4096
#define DIM   64
#define MTILE 64              // q rows per workgroup (4 waves x 16)
#define KVB   64              // key chunk
#define NCH   (SEQ / KVB)     // 64 chunks
#define EL_CH 4096            // elems per chunk per tensor (512 frags * 8)
#define EL_B  (NCH * EL_CH)   // elems per batch per tensor (262144)

__device__ __forceinline__ short f2bf(float f) {
    unsigned u = __builtin_bit_cast(unsigned, f);
    u += 0x7FFF + ((u >> 16) & 1);          // round-to-nearest-even
    return (short)(u >> 16);
}
__device__ __forceinline__ float bf2f(short h) {
    return __builtin_bit_cast(float, (unsigned)((unsigned short)h) << 16);
}

__device__ __forceinline__ void gld16(const void* g, void* l) {
    __builtin_amdgcn_global_load_lds(
        (const __attribute__((address_space(1))) unsigned int*)g,
        (__attribute__((address_space(3))) unsigned int*)l, 16, 0, 0);
}

// ======== pre-kernel: K,V -> fp16 frag-linear ========
// K frag(ch,nf,kk,lane) = K[ch*64 + nf*16 + (lane&15)][kk*32 + (lane>>4)*8 + e]
// V frag(ch,nf,kk,lane) = V[ch*64 + kk*32 + (lane>>4)*8 + e][nf*16 + (lane&15)]
__global__ __launch_bounds__(256) void preconvert(
    const float* __restrict__ k, const float* __restrict__ v,
    _Float16* __restrict__ kh, _Float16* __restrict__ vh)
{
    int f = blockIdx.x * 256 + threadIdx.x;   // 0 .. 2*524288-1
    int lane = f & 63;
    int sub  = (f >> 6) & 7;                  // nf*2 + kk
    int ch   = (f >> 9) & 63;
    int bb   = (f >> 15) & 15;
    int isV  = f >> 19;
    int nf = sub >> 1, kk = sub & 1;
    size_t fo = (size_t)(f & ((1 << 19) - 1)) * 8;

    if (!isV) {
        int key = ch * 64 + nf * 16 + (lane & 15);
        int d0  = kk * 32 + (lane >> 4) * 8;
        const float* src = k + (((size_t)bb * SEQ + key) * DIM + d0);
        half8 h8;
        #pragma unroll
        for (int e = 0; e < 8; ++e) h8[e] = (_Float16)src[e];
        *(half8*)(kh + fo) = h8;
    } else {
        int kr0 = kk * 32 + (lane >> 4) * 8;
        int d   = nf * 16 + (lane & 15);
        const float* src = v + (((size_t)bb * SEQ + ch * 64 + kr0) * DIM + d);
        half8 h8;
        #pragma unroll
        for (int e = 0; e < 8; ++e) h8[e] = (_Float16)src[e * DIM];
        *(half8*)(vh + fo) = h8;
    }
}

// ============================== main kernel ==============================
__global__ __launch_bounds__(256) void attn_main(
    const float* __restrict__ q, const _Float16* __restrict__ kh,
    const _Float16* __restrict__ vh, float* __restrict__ ctx,
    float* __restrict__ att)
{
    __shared__ _Float16 Kst[2][EL_CH];    // fp16 K chunk, double-buffered (16 KB)
    __shared__ _Float16 Vst[2][EL_CH];    // fp16 V^T chunk (16 KB)
    __shared__ _Float16 Ph[4][16][72];    // per-wave P fp16 (stride 144B) (9 KB)

    int id = blockIdx.x;                  // grid = 1024
    int bb = (id & 7) + 8 * (id >> 9);    // XCD-swizzled batch
    int qt = (id >> 3) & 63;

    int tid = threadIdx.x;
    int w = tid >> 6, lane = tid & 63, li = lane & 15, h4 = lane >> 4;

    // ---- Q A-fragments (fp16) in registers for the whole kernel ----
    int qrow = qt * MTILE + w * 16 + li;
    const float* qp = q + ((size_t)bb * SEQ + qrow) * DIM;
    half8 aq[2];
    #pragma unroll
    for (int kk = 0; kk < 2; ++kk)
        #pragma unroll
        for (int e = 0; e < 8; ++e)
            aq[kk][e] = (_Float16)qp[kk * 32 + h4 * 8 + e];

    const _Float16* khb = kh + (size_t)bb * EL_B;
    const _Float16* vvb = vh + (size_t)bb * EL_B;

    auto stage_k = [&](int buf, int ch) {
        const _Float16* g = khb + (size_t)ch * EL_CH + tid * 8;
        gld16(g,        &Kst[buf][w * 512]);
        gld16(g + 2048, &Kst[buf][2048 + w * 512]);
    };
    auto stage_v = [&](int buf, int ch) {
        const _Float16* g = vvb + (size_t)ch * EL_CH + tid * 8;
        gld16(g,        &Vst[buf][w * 512]);
        gld16(g + 2048, &Vst[buf][2048 + w * 512]);
    };
    // fp16 QK^T from frag-linear LDS (identical in both passes)
    auto qkt = [&](int buf, f32x4* s) {
        const half8* k8 = (const half8*)&Kst[buf][0];
        #pragma unroll
        for (int kk = 0; kk < 2; ++kk)
            #pragma unroll
            for (int nf = 0; nf < 4; ++nf)
                s[nf] = __builtin_amdgcn_mfma_f32_16x16x32_f16(
                    aq[kk], k8[(nf * 2 + kk) * 64 + lane], s[nf], 0, 0, 0);
    };

    // ========== pass 1: l = sum exp(s)  (max-free: |s| <~ 60, fp32 safe) ====
    float ll[4] = {0.f, 0.f, 0.f, 0.f};

    stage_k(0, 0);
    for (int ch = 0; ch < NCH; ++ch) {
        int buf = ch & 1;
        if (ch + 1 < NCH) {
            stage_k(buf ^ 1, ch + 1);
            asm volatile("s_waitcnt vmcnt(2)" ::: "memory");
        } else {
            asm volatile("s_waitcnt vmcnt(0)" ::: "memory");
        }
        __builtin_amdgcn_s_barrier();
        asm volatile("" ::: "memory");

        f32x4 s[4];
        #pragma unroll
        for (int nf = 0; nf < 4; ++nf) s[nf] = (f32x4){0.f, 0.f, 0.f, 0.f};
        qkt(buf, s);

        #pragma unroll
        for (int r = 0; r < 4; ++r)
            ll[r] += (__expf(s[0][r]) + __expf(s[1][r]))
                   + (__expf(s[2][r]) + __expf(s[3][r]));

        asm volatile("" ::: "memory");
        __builtin_amdgcn_s_barrier();
    }

    // sum l across the 16-lane key group, invert
    float rl[4];
    #pragma unroll
    for (int r = 0; r < 4; ++r) {
        float s0 = ll[r];
        #pragma unroll
        for (int st = 1; st < 16; st <<= 1) s0 += __shfl_xor(s0, st);
        rl[r] = 1.0f / s0;
    }

    // ========== pass 2: p = exp(s)*rl; att stores from fp16 P; PV fp16 =====
    f32x4 acc[4];
    #pragma unroll
    for (int nf = 0; nf < 4; ++nf) acc[nf] = (f32x4){0.f, 0.f, 0.f, 0.f};

    float* attb = att + ((size_t)bb * SEQ + (size_t)qt * MTILE + w * 16) * SEQ;
    int sr = lane >> 3, sc8 = (lane & 7) * 8;

    stage_k(0, 0); stage_v(0, 0);
    for (int ch = 0; ch < NCH; ++ch) {
        int buf = ch & 1;
        if (ch + 1 < NCH) {
            stage_k(buf ^ 1, ch + 1);
            stage_v(buf ^ 1, ch + 1);
            // queue: [4 loads cur][4 stores prev][4 loads next]
            // vmcnt(8): cur loads retired; stores + next loads ride.
            if (ch == 0) asm volatile("s_waitcnt vmcnt(4)" ::: "memory");
            else         asm volatile("s_waitcnt vmcnt(8)" ::: "memory");
        } else {
            // queue: [4 loads cur][4 stores prev] -> need cur only
            asm volatile("s_waitcnt vmcnt(4)" ::: "memory");
        }
        __builtin_amdgcn_s_barrier();
        asm volatile("" ::: "memory");

        f32x4 s[4];
        #pragma unroll
        for (int nf = 0; nf < 4; ++nf) s[nf] = (f32x4){0.f, 0.f, 0.f, 0.f};
        qkt(buf, s);

        // p = exp(s) * rl -> Ph (fp16): single source of truth for att + PV
        #pragma unroll
        for (int nf = 0; nf < 4; ++nf)
            #pragma unroll
            for (int r = 0; r < 4; ++r)
                Ph[w][4 * h4 + r][nf * 16 + li] =
                    (_Float16)(__expf(s[nf][r]) * rl[r]);

        // att stores: read fp16 P rows (b128), convert, 256B runs per row
        #pragma unroll
        for (int j = 0; j < 2; ++j) {
            int row = j * 8 + sr;
            half8 ph = *(const half8*)&Ph[w][row][sc8];
            f32x4 lo = { (float)ph[0], (float)ph[1], (float)ph[2], (float)ph[3] };
            f32x4 hi = { (float)ph[4], (float)ph[5], (float)ph[6], (float)ph[7] };
            float* dst = attb + (size_t)row * SEQ + ch * KVB + sc8;
            __builtin_nontemporal_store(lo, (f32x4*)dst);
            __builtin_nontemporal_store(hi, (f32x4*)(dst + 4));
        }

        // PV (fp16): acc[q][d] += P[q][key] * V[key][d]
        const half8* v8 = (const half8*)&Vst[buf][0];
        #pragma unroll
        for (int kk = 0; kk < 2; ++kk) {
            half8 pa = *(const half8*)&Ph[w][li][kk * 32 + h4 * 8];
            #pragma unroll
            for (int nf = 0; nf < 4; ++nf)
                acc[nf] = __builtin_amdgcn_mfma_f32_16x16x32_f16(
                    pa, v8[(nf * 2 + kk) * 64 + lane], acc[nf], 0, 0, 0);
        }

        asm volatile("" ::: "memory");
        __builtin_amdgcn_s_barrier();
    }

    float* ctxb = ctx + ((size_t)bb * SEQ + (size_t)qt * MTILE + w * 16) * DIM;
    #pragma unroll
    for (int nf = 0; nf < 4; ++nf)
        #pragma unroll
        for (int r = 0; r < 4; ++r)
            __builtin_nontemporal_store(
                acc[nf][r], &ctxb[(size_t)(4 * h4 + r) * DIM + nf * 16 + li]);
}

// ===================== fallback (round-2 kernel, proven) =====================
__global__ __launch_bounds__(256) void attn_fallback(
    const float* __restrict__ q, const float* __restrict__ k,
    const float* __restrict__ v, float* __restrict__ ctx,
    float* __restrict__ att)
{
    __shared__ short K_hi[KVB][72];
    __shared__ short K_lo[KVB][72];
    __shared__ short V_lds[DIM][72];
    __shared__ short P_lds[4][16][72];

    int id = blockIdx.x;
    int bb = (id & 7) + 8 * (id >> 9);
    int qt = (id >> 3) & 63;
    int tid = threadIdx.x;
    int w = tid >> 6, lane = tid & 63, li = lane & 15, h4 = lane >> 4;

    int qrow = qt * 64 + w * 16 + li;
    const float* qp = q + ((size_t)bb * SEQ + qrow) * DIM;
    short8 aq[2], aql[2];
    #pragma unroll
    for (int kk = 0; kk < 2; ++kk)
        #pragma unroll
        for (int e = 0; e < 8; ++e) {
            float x = qp[kk * 32 + h4 * 8 + e];
            short h = f2bf(x);
            aq[kk][e] = h; aql[kk][e] = f2bf(x - bf2f(h));
        }

    float m[4], l[4];
    #pragma unroll
    for (int r = 0; r < 4; ++r) { m[r] = -3.0e38f; l[r] = 0.0f; }
    const float* kbase = k + (size_t)bb * SEQ * DIM;
    const float* vbase = v + (size_t)bb * SEQ * DIM;

    for (int ch = 0; ch < NCH; ++ch) {
        __syncthreads();
        const float4* kc = (const float4*)(kbase + (size_t)ch * KVB * DIM);
        #pragma unroll
        for (int j = 0; j < 4; ++j) {
            int f4 = j * 256 + tid; int key = f4 >> 4, d4 = f4 & 15;
            float4 val = kc[f4];
            short4v h4v, l4v;
            h4v[0]=f2bf(val.x); l4v[0]=f2bf(val.x-bf2f(h4v[0]));
            h4v[1]=f2bf(val.y); l4v[1]=f2bf(val.y-bf2f(h4v[1]));
            h4v[2]=f2bf(val.z); l4v[2]=f2bf(val.z-bf2f(h4v[2]));
            h4v[3]=f2bf(val.w); l4v[3]=f2bf(val.w-bf2f(h4v[3]));
            *(short4v*)&K_hi[key][d4*4] = h4v;
            *(short4v*)&K_lo[key][d4*4] = l4v;
        }
        __syncthreads();
        f32x4 s[4];
        #pragma unroll
        for (int nf = 0; nf < 4; ++nf) s[nf] = (f32x4){0.f,0.f,0.f,0.f};
        #pragma unroll
        for (int kk = 0; kk < 2; ++kk)
            #pragma unroll
            for (int nf = 0; nf < 4; ++nf) {
                short8 kbv = *(const short8*)&K_hi[nf*16+li][kk*32+h4*8];
                short8 klv = *(const short8*)&K_lo[nf*16+li][kk*32+h4*8];
                s[nf] = __builtin_amdgcn_mfma_f32_16x16x32_bf16(aq[kk],  kbv, s[nf],0,0,0);
                s[nf] = __builtin_amdgcn_mfma_f32_16x16x32_bf16(aq[kk],  klv, s[nf],0,0,0);
                s[nf] = __builtin_amdgcn_mfma_f32_16x16x32_bf16(aql[kk], kbv, s[nf],0,0,0);
            }
        #pragma unroll
        for (int r = 0; r < 4; ++r) {
            float cmax = fmaxf(fmaxf(s[0][r],s[1][r]), fmaxf(s[2][r],s[3][r]));
            #pragma unroll
            for (int off = 1; off < 16; off <<= 1) cmax = fmaxf(cmax, __shfl_xor(cmax, off));
            float mnew = fmaxf(m[r], cmax);
            float cs = __expf(s[0][r]-mnew)+__expf(s[1][r]-mnew)+__expf(s[2][r]-mnew)+__expf(s[3][r]-mnew);
            #pragma unroll
            for (int off = 1; off < 16; off <<= 1) cs += __shfl_xor(cs, off);
            l[r] = l[r]*__expf(m[r]-mnew) + cs; m[r] = mnew;
        }
    }
    float rl[4];
    #pragma unroll
    for (int r = 0; r < 4; ++r) rl[r] = 1.0f / l[r];

    f32x4 acc[4];
    #pragma unroll
    for (int nf = 0; nf < 4; ++nf) acc[nf] = (f32x4){0.f,0.f,0.f,0.f};
    float* attb = att + ((size_t)bb * SEQ + (size_t)qt * 64 + w * 16) * SEQ;

    for (int ch = 0; ch < NCH; ++ch) {
        __syncthreads();
        const float4* kc = (const float4*)(kbase + (size_t)ch * KVB * DIM);
        #pragma unroll
        for (int j = 0; j < 4; ++j) {
            int f4 = j * 256 + tid; int key = f4 >> 4, d4 = f4 & 15;
            float4 val = kc[f4];
            short4v h4v, l4v;
            h4v[0]=f2bf(val.x); l4v[0]=f2bf(val.x-bf2f(h4v[0]));
            h4v[1]=f2bf(val.y); l4v[1]=f2bf(val.y-bf2f(h4v[1]));
            h4v[2]=f2bf(val.z); l4v[2]=f2bf(val.z-bf2f(h4v[2]));
            h4v[3]=f2bf(val.w); l4v[3]=f2bf(val.w-bf2f(h4v[3]));
            *(short4v*)&K_hi[key][d4*4] = h4v;
            *(short4v*)&K_lo[key][d4*4] = l4v;
        }
        {
            int key = tid & 63, dblk = (tid >> 6) * 16;
            const float* vc = vbase + ((size_t)ch * KVB + key) * DIM + dblk;
            #pragma unroll
            for (int j = 0; j < 4; ++j) {
                float4 val = *(const float4*)(vc + j * 4);
                V_lds[dblk+j*4+0][key]=f2bf(val.x); V_lds[dblk+j*4+1][key]=f2bf(val.y);
                V_lds[dblk+j*4+2][key]=f2bf(val.z); V_lds[dblk+j*4+3][key]=f2bf(val.w);
            }
        }
        __syncthreads();
        f32x4 s[4];
        #pragma unroll
        for (int nf = 0; nf < 4; ++nf) s[nf] = (f32x4){0.f,0.f,0.f,0.f};
        #pragma unroll
        for (int kk = 0; kk < 2; ++kk)
            #pragma unroll
            for (int nf = 0; nf < 4; ++nf) {
                short8 kbv = *(const short8*)&K_hi[nf*16+li][kk*32+h4*8];
                short8 klv = *(const short8*)&K_lo[nf*16+li][kk*32+h4*8];
                s[nf] = __builtin_amdgcn_mfma_f32_16x16x32_bf16(aq[kk],  kbv, s[nf],0,0,0);
                s[nf] = __builtin_amdgcn_mfma_f32_16x16x32_bf16(aq[kk],  klv, s[nf],0,0,0);
                s[nf] = __builtin_amdgcn_mfma_f32_16x16x32_bf16(aql[kk], kbv, s[nf],0,0,0);
            }
        #pragma unroll
        for (int nf = 0; nf < 4; ++nf)
            #pragma unroll
            for (int r = 0; r < 4; ++r) {
                float p = __expf(s[nf][r] - m[r]) * rl[r];
                __builtin_nontemporal_store(p, &attb[(size_t)(4*h4+r)*SEQ + ch*KVB + nf*16 + li]);
                P_lds[w][4*h4+r][nf*16+li] = f2bf(p);
            }
        #pragma unroll
        for (int kk = 0; kk < 2; ++kk) {
            short8 pa = *(const short8*)&P_lds[w][li][kk*32+h4*8];
            #pragma unroll
            for (int nf = 0; nf < 4; ++nf) {
                short8 vbv = *(const short8*)&V_lds[nf*16+li][kk*32+h4*8];
                acc[nf] = __builtin_amdgcn_mfma_f32_16x16x32_bf16(pa, vbv, acc[nf],0,0,0);
            }
        }
    }
    float* ctxb = ctx + ((size_t)bb * SEQ + (size_t)qt * 64 + w * 16) * DIM;
    #pragma unroll
    for (int nf = 0; nf < 4; ++nf)
        #pragma unroll
        for (int r = 0; r < 4; ++r)
            __builtin_nontemporal_store(acc[nf][r], &ctxb[(size_t)(4*h4+r)*DIM + nf*16 + li]);
}

extern "C" void kernel_launch(void* const* d_in, const int* in_sizes, int n_in,
                              void* d_out, int out_size, void* d_ws, size_t ws_size,
                              hipStream_t stream) {
    const float* q = (const float*)d_in[0];
    const float* k = (const float*)d_in[1];
    const float* v = (const float*)d_in[2];
    float* ctx = (float*)d_out;
    float* att = (float*)d_out + (size_t)BATCH * SEQ * DIM;

    const size_t t_el = (size_t)BATCH * EL_B;              // 4,194,304
    const size_t need = 2 * t_el * 2;                      // 16.8 MB

    if (ws_size >= need) {
        _Float16* kh = (_Float16*)d_ws;
        _Float16* vh = kh + t_el;
        preconvert<<<4096, 256, 0, stream>>>(k, v, kh, vh);
        attn_main<<<BATCH * (SEQ / MTILE), 256, 0, stream>>>(q, kh, vh, ctx, att);
    } else {
        attn_fallback<<<BATCH * (SEQ / 64), 256, 0, stream>>>(q, k, v, ctx, att);
    }
}

// Round 10
// 309.498 us; speedup vs baseline: 1.6716x; 1.6716x over previous
//
#include <hip/hip_runtime.h>
#include <hip/hip_bf16.h>

typedef _Float16 half8 __attribute__((ext_vector_type(8)));
typedef _Float16 half4 __attribute__((ext_vector_type(4)));
typedef short short8 __attribute__((ext_vector_type(8)));
typedef short short4v __attribute__((ext_vector_type(4)));
typedef float f32x4 __attribute__((ext_vector_type(4)));

#define BATCH 16
#define SEQ   4096
#define DIM   64
#define MTILE 64              // q rows per workgroup (4 waves x 16)
#define KVB   64              // key chunk
#define NCH   (SEQ / KVB)     // 64 chunks
#define EL_CH 4096            // elems per chunk per tensor (512 frags * 8)
#define EL_B  (NCH * EL_CH)   // elems per batch per tensor (262144)

__device__ __forceinline__ short f2bf(float f) {
    unsigned u = __builtin_bit_cast(unsigned, f);
    u += 0x7FFF + ((u >> 16) & 1);          // round-to-nearest-even
    return (short)(u >> 16);
}
__device__ __forceinline__ float bf2f(short h) {
    return __builtin_bit_cast(float, (unsigned)((unsigned short)h) << 16);
}

__device__ __forceinline__ void gld16(const void* g, void* l) {
    __builtin_amdgcn_global_load_lds(
        (const __attribute__((address_space(1))) unsigned int*)g,
        (__attribute__((address_space(3))) unsigned int*)l, 16, 0, 0);
}

// ======== pre-kernel: K,V -> fp16 frag-linear ========
// K frag(ch,nf,kk,lane) = K[ch*64 + nf*16 + (lane&15)][kk*32 + (lane>>4)*8 + e]
// V frag(ch,nf,kk,lane) = V[ch*64 + kk*32 + (lane>>4)*8 + e][nf*16 + (lane&15)]
__global__ __launch_bounds__(256) void preconvert(
    const float* __restrict__ k, const float* __restrict__ v,
    _Float16* __restrict__ kh, _Float16* __restrict__ vh)
{
    int f = blockIdx.x * 256 + threadIdx.x;   // 0 .. 2*524288-1
    int lane = f & 63;
    int sub  = (f >> 6) & 7;                  // nf*2 + kk
    int ch   = (f >> 9) & 63;
    int bb   = (f >> 15) & 15;
    int isV  = f >> 19;
    int nf = sub >> 1, kk = sub & 1;
    size_t fo = (size_t)(f & ((1 << 19) - 1)) * 8;

    if (!isV) {
        int key = ch * 64 + nf * 16 + (lane & 15);
        int d0  = kk * 32 + (lane >> 4) * 8;
        const float* src = k + (((size_t)bb * SEQ + key) * DIM + d0);
        half8 h8;
        #pragma unroll
        for (int e = 0; e < 8; ++e) h8[e] = (_Float16)src[e];
        *(half8*)(kh + fo) = h8;
    } else {
        int kr0 = kk * 32 + (lane >> 4) * 8;
        int d   = nf * 16 + (lane & 15);
        const float* src = v + (((size_t)bb * SEQ + ch * 64 + kr0) * DIM + d);
        half8 h8;
        #pragma unroll
        for (int e = 0; e < 8; ++e) h8[e] = (_Float16)src[e * DIM];
        *(half8*)(vh + fo) = h8;
    }
}

// ============================== main kernel ==============================
__global__ __launch_bounds__(256) void attn_main(
    const float* __restrict__ q, const _Float16* __restrict__ kh,
    const _Float16* __restrict__ vh, float* __restrict__ ctx,
    float* __restrict__ att)
{
    __shared__ _Float16 Kst[2][EL_CH];    // fp16 K chunk, double-buffered (16 KB)
    __shared__ _Float16 Vst[2][EL_CH];    // fp16 V^T chunk (16 KB)
    __shared__ _Float16 Ph[4][16][72];    // per-wave P fp16 (stride 144B) (9 KB)

    int id = blockIdx.x;                  // grid = 1024
    int bb = (id & 7) + 8 * (id >> 9);    // XCD-swizzled batch
    int qt = (id >> 3) & 63;

    int tid = threadIdx.x;
    int w = tid >> 6, lane = tid & 63, li = lane & 15, h4 = lane >> 4;

    // ---- Q A-fragments (fp16) in registers for the whole kernel ----
    int qrow = qt * MTILE + w * 16 + li;
    const float* qp = q + ((size_t)bb * SEQ + qrow) * DIM;
    half8 aq[2];
    #pragma unroll
    for (int kk = 0; kk < 2; ++kk)
        #pragma unroll
        for (int e = 0; e < 8; ++e)
            aq[kk][e] = (_Float16)qp[kk * 32 + h4 * 8 + e];

    const _Float16* khb = kh + (size_t)bb * EL_B;
    const _Float16* vvb = vh + (size_t)bb * EL_B;

    auto stage_k = [&](int buf, int ch) {
        const _Float16* g = khb + (size_t)ch * EL_CH + tid * 8;
        gld16(g,        &Kst[buf][w * 512]);
        gld16(g + 2048, &Kst[buf][2048 + w * 512]);
    };
    auto stage_v = [&](int buf, int ch) {
        const _Float16* g = vvb + (size_t)ch * EL_CH + tid * 8;
        gld16(g,        &Vst[buf][w * 512]);
        gld16(g + 2048, &Vst[buf][2048 + w * 512]);
    };
    // fp16 QK^T from frag-linear LDS (identical in both passes)
    auto qkt = [&](int buf, f32x4* s) {
        const half8* k8 = (const half8*)&Kst[buf][0];
        #pragma unroll
        for (int kk = 0; kk < 2; ++kk)
            #pragma unroll
            for (int nf = 0; nf < 4; ++nf)
                s[nf] = __builtin_amdgcn_mfma_f32_16x16x32_f16(
                    aq[kk], k8[(nf * 2 + kk) * 64 + lane], s[nf], 0, 0, 0);
    };

    // ========== pass 1: l = sum exp(s)  (max-free: |s| <~ 60, fp32 safe) ====
    float ll[4] = {0.f, 0.f, 0.f, 0.f};

    stage_k(0, 0);
    for (int ch = 0; ch < NCH; ++ch) {
        int buf = ch & 1;
        if (ch + 1 < NCH) {
            stage_k(buf ^ 1, ch + 1);
            asm volatile("s_waitcnt vmcnt(2)" ::: "memory");
        } else {
            asm volatile("s_waitcnt vmcnt(0)" ::: "memory");
        }
        __builtin_amdgcn_s_barrier();
        asm volatile("" ::: "memory");

        f32x4 s[4];
        #pragma unroll
        for (int nf = 0; nf < 4; ++nf) s[nf] = (f32x4){0.f, 0.f, 0.f, 0.f};
        qkt(buf, s);

        #pragma unroll
        for (int r = 0; r < 4; ++r)
            ll[r] += (__expf(s[0][r]) + __expf(s[1][r]))
                   + (__expf(s[2][r]) + __expf(s[3][r]));

        asm volatile("" ::: "memory");
        __builtin_amdgcn_s_barrier();
    }

    // sum l across the 16-lane key group, invert
    float rl[4];
    #pragma unroll
    for (int r = 0; r < 4; ++r) {
        float s0 = ll[r];
        #pragma unroll
        for (int st = 1; st < 16; st <<= 1) s0 += __shfl_xor(s0, st);
        rl[r] = 1.0f / s0;
    }

    // ========== pass 2: p = exp(s)*rl; att stores (16-lane dense); PV fp16 ==
    f32x4 acc[4];
    #pragma unroll
    for (int nf = 0; nf < 4; ++nf) acc[nf] = (f32x4){0.f, 0.f, 0.f, 0.f};

    float* attb = att + ((size_t)bb * SEQ + (size_t)qt * MTILE + w * 16) * SEQ;

    stage_k(0, 0); stage_v(0, 0);
    for (int ch = 0; ch < NCH; ++ch) {
        int buf = ch & 1;
        if (ch + 1 < NCH) {
            stage_k(buf ^ 1, ch + 1);
            stage_v(buf ^ 1, ch + 1);
            // queue: [4 loads cur][4 stores prev][4 loads next]
            // vmcnt(8): cur loads retired; stores + next loads ride.
            if (ch == 0) asm volatile("s_waitcnt vmcnt(4)" ::: "memory");
            else         asm volatile("s_waitcnt vmcnt(8)" ::: "memory");
        } else {
            // queue: [4 loads cur][4 stores prev] -> need cur only
            asm volatile("s_waitcnt vmcnt(4)" ::: "memory");
        }
        __builtin_amdgcn_s_barrier();
        asm volatile("" ::: "memory");

        f32x4 s[4];
        #pragma unroll
        for (int nf = 0; nf < 4; ++nf) s[nf] = (f32x4){0.f, 0.f, 0.f, 0.f};
        qkt(buf, s);

        // p = exp(s) * rl -> Ph (fp16): single source of truth for att + PV
        #pragma unroll
        for (int nf = 0; nf < 4; ++nf)
            #pragma unroll
            for (int r = 0; r < 4; ++r)
                Ph[w][4 * h4 + r][nf * 16 + li] =
                    (_Float16)(__expf(s[nf][r]) * rl[r]);

        // att stores, 16-lane contiguous: lane li covers [li*4, li*4+4) of a
        // 256B row -> one dense f32x4 NT store instruction per row.
        #pragma unroll
        for (int j = 0; j < 4; ++j) {
            int row = j * 4 + h4;
            half4 ph = *(const half4*)&Ph[w][row][li * 4];
            f32x4 pv = { (float)ph[0], (float)ph[1], (float)ph[2], (float)ph[3] };
            __builtin_nontemporal_store(
                pv, (f32x4*)(attb + (size_t)row * SEQ + ch * KVB + li * 4));
        }

        // PV (fp16): acc[q][d] += P[q][key] * V[key][d]
        const half8* v8 = (const half8*)&Vst[buf][0];
        #pragma unroll
        for (int kk = 0; kk < 2; ++kk) {
            half8 pa = *(const half8*)&Ph[w][li][kk * 32 + h4 * 8];
            #pragma unroll
            for (int nf = 0; nf < 4; ++nf)
                acc[nf] = __builtin_amdgcn_mfma_f32_16x16x32_f16(
                    pa, v8[(nf * 2 + kk) * 64 + lane], acc[nf], 0, 0, 0);
        }

        asm volatile("" ::: "memory");
        __builtin_amdgcn_s_barrier();
    }

    float* ctxb = ctx + ((size_t)bb * SEQ + (size_t)qt * MTILE + w * 16) * DIM;
    #pragma unroll
    for (int nf = 0; nf < 4; ++nf)
        #pragma unroll
        for (int r = 0; r < 4; ++r)
            __builtin_nontemporal_store(
                acc[nf][r], &ctxb[(size_t)(4 * h4 + r) * DIM + nf * 16 + li]);
}

// ===================== fallback (round-2 kernel, proven) =====================
__global__ __launch_bounds__(256) void attn_fallback(
    const float* __restrict__ q, const float* __restrict__ k,
    const float* __restrict__ v, float* __restrict__ ctx,
    float* __restrict__ att)
{
    __shared__ short K_hi[KVB][72];
    __shared__ short K_lo[KVB][72];
    __shared__ short V_lds[DIM][72];
    __shared__ short P_lds[4][16][72];

    int id = blockIdx.x;
    int bb = (id & 7) + 8 * (id >> 9);
    int qt = (id >> 3) & 63;
    int tid = threadIdx.x;
    int w = tid >> 6, lane = tid & 63, li = lane & 15, h4 = lane >> 4;

    int qrow = qt * 64 + w * 16 + li;
    const float* qp = q + ((size_t)bb * SEQ + qrow) * DIM;
    short8 aq[2], aql[2];
    #pragma unroll
    for (int kk = 0; kk < 2; ++kk)
        #pragma unroll
        for (int e = 0; e < 8; ++e) {
            float x = qp[kk * 32 + h4 * 8 + e];
            short h = f2bf(x);
            aq[kk][e] = h; aql[kk][e] = f2bf(x - bf2f(h));
        }

    float m[4], l[4];
    #pragma unroll
    for (int r = 0; r < 4; ++r) { m[r] = -3.0e38f; l[r] = 0.0f; }
    const float* kbase = k + (size_t)bb * SEQ * DIM;
    const float* vbase = v + (size_t)bb * SEQ * DIM;

    for (int ch = 0; ch < NCH; ++ch) {
        __syncthreads();
        const float4* kc = (const float4*)(kbase + (size_t)ch * KVB * DIM);
        #pragma unroll
        for (int j = 0; j < 4; ++j) {
            int f4 = j * 256 + tid; int key = f4 >> 4, d4 = f4 & 15;
            float4 val = kc[f4];
            short4v h4v, l4v;
            h4v[0]=f2bf(val.x); l4v[0]=f2bf(val.x-bf2f(h4v[0]));
            h4v[1]=f2bf(val.y); l4v[1]=f2bf(val.y-bf2f(h4v[1]));
            h4v[2]=f2bf(val.z); l4v[2]=f2bf(val.z-bf2f(h4v[2]));
            h4v[3]=f2bf(val.w); l4v[3]=f2bf(val.w-bf2f(h4v[3]));
            *(short4v*)&K_hi[key][d4*4] = h4v;
            *(short4v*)&K_lo[key][d4*4] = l4v;
        }
        __syncthreads();
        f32x4 s[4];
        #pragma unroll
        for (int nf = 0; nf < 4; ++nf) s[nf] = (f32x4){0.f,0.f,0.f,0.f};
        #pragma unroll
        for (int kk = 0; kk < 2; ++kk)
            #pragma unroll
            for (int nf = 0; nf < 4; ++nf) {
                short8 kbv = *(const short8*)&K_hi[nf*16+li][kk*32+h4*8];
                short8 klv = *(const short8*)&K_lo[nf*16+li][kk*32+h4*8];
                s[nf] = __builtin_amdgcn_mfma_f32_16x16x32_bf16(aq[kk],  kbv, s[nf],0,0,0);
                s[nf] = __builtin_amdgcn_mfma_f32_16x16x32_bf16(aq[kk],  klv, s[nf],0,0,0);
                s[nf] = __builtin_amdgcn_mfma_f32_16x16x32_bf16(aql[kk], kbv, s[nf],0,0,0);
            }
        #pragma unroll
        for (int r = 0; r < 4; ++r) {
            float cmax = fmaxf(fmaxf(s[0][r],s[1][r]), fmaxf(s[2][r],s[3][r]));
            #pragma unroll
            for (int off = 1; off < 16; off <<= 1) cmax = fmaxf(cmax, __shfl_xor(cmax, off));
            float mnew = fmaxf(m[r], cmax);
            float cs = __expf(s[0][r]-mnew)+__expf(s[1][r]-mnew)+__expf(s[2][r]-mnew)+__expf(s[3][r]-mnew);
            #pragma unroll
            for (int off = 1; off < 16; off <<= 1) cs += __shfl_xor(cs, off);
            l[r] = l[r]*__expf(m[r]-mnew) + cs; m[r] = mnew;
        }
    }
    float rl[4];
    #pragma unroll
    for (int r = 0; r < 4; ++r) rl[r] = 1.0f / l[r];

    f32x4 acc[4];
    #pragma unroll
    for (int nf = 0; nf < 4; ++nf) acc[nf] = (f32x4){0.f,0.f,0.f,0.f};
    float* attb = att + ((size_t)bb * SEQ + (size_t)qt * 64 + w * 16) * SEQ;

    for (int ch = 0; ch < NCH; ++ch) {
        __syncthreads();
        const float4* kc = (const float4*)(kbase + (size_t)ch * KVB * DIM);
        #pragma unroll
        for (int j = 0; j < 4; ++j) {
            int f4 = j * 256 + tid; int key = f4 >> 4, d4 = f4 & 15;
            float4 val = kc[f4];
            short4v h4v, l4v;
            h4v[0]=f2bf(val.x); l4v[0]=f2bf(val.x-bf2f(h4v[0]));
            h4v[1]=f2bf(val.y); l4v[1]=f2bf(val.y-bf2f(h4v[1]));
            h4v[2]=f2bf(val.z); l4v[2]=f2bf(val.z-bf2f(h4v[2]));
            h4v[3]=f2bf(val.w); l4v[3]=f2bf(val.w-bf2f(h4v[3]));
            *(short4v*)&K_hi[key][d4*4] = h4v;
            *(short4v*)&K_lo[key][d4*4] = l4v;
        }
        {
            int key = tid & 63, dblk = (tid >> 6) * 16;
            const float* vc = vbase + ((size_t)ch * KVB + key) * DIM + dblk;
            #pragma unroll
            for (int j = 0; j < 4; ++j) {
                float4 val = *(const float4*)(vc + j * 4);
                V_lds[dblk+j*4+0][key]=f2bf(val.x); V_lds[dblk+j*4+1][key]=f2bf(val.y);
                V_lds[dblk+j*4+2][key]=f2bf(val.z); V_lds[dblk+j*4+3][key]=f2bf(val.w);
            }
        }
        __syncthreads();
        f32x4 s[4];
        #pragma unroll
        for (int nf = 0; nf < 4; ++nf) s[nf] = (f32x4){0.f,0.f,0.f,0.f};
        #pragma unroll
        for (int kk = 0; kk < 2; ++kk)
            #pragma unroll
            for (int nf = 0; nf < 4; ++nf) {
                short8 kbv = *(const short8*)&K_hi[nf*16+li][kk*32+h4*8];
                short8 klv = *(const short8*)&K_lo[nf*16+li][kk*32+h4*8];
                s[nf] = __builtin_amdgcn_mfma_f32_16x16x32_bf16(aq[kk],  kbv, s[nf],0,0,0);
                s[nf] = __builtin_amdgcn_mfma_f32_16x16x32_bf16(aq[kk],  klv, s[nf],0,0,0);
                s[nf] = __builtin_amdgcn_mfma_f32_16x16x32_bf16(aql[kk], kbv, s[nf],0,0,0);
            }
        #pragma unroll
        for (int nf = 0; nf < 4; ++nf)
            #pragma unroll
            for (int r = 0; r < 4; ++r) {
                float p = __expf(s[nf][r] - m[r]) * rl[r];
                __builtin_nontemporal_store(p, &attb[(size_t)(4*h4+r)*SEQ + ch*KVB + nf*16 + li]);
                P_lds[w][4*h4+r][nf*16+li] = f2bf(p);
            }
        #pragma unroll
        for (int kk = 0; kk < 2; ++kk) {
            short8 pa = *(const short8*)&P_lds[w][li][kk*32+h4*8];
            #pragma unroll
            for (int nf = 0; nf < 4; ++nf) {
                short8 vbv = *(const short8*)&V_lds[nf*16+li][kk*32+h4*8];
                acc[nf] = __builtin_amdgcn_mfma_f32_16x16x32_bf16(pa, vbv, acc[nf],0,0,0);
            }
        }
    }
    float* ctxb = ctx + ((size_t)bb * SEQ + (size_t)qt * 64 + w * 16) * DIM;
    #pragma unroll
    for (int nf = 0; nf < 4; ++nf)
        #pragma unroll
        for (int r = 0; r < 4; ++r)
            __builtin_nontemporal_store(acc[nf][r], &ctxb[(size_t)(4*h4+r)*DIM + nf*16 + li]);
}

extern "C" void kernel_launch(void* const* d_in, const int* in_sizes, int n_in,
                              void* d_out, int out_size, void* d_ws, size_t ws_size,
                              hipStream_t stream) {
    const float* q = (const float*)d_in[0];
    const float* k = (const float*)d_in[1];
    const float* v = (const float*)d_in[2];
    float* ctx = (float*)d_out;
    float* att = (float*)d_out + (size_t)BATCH * SEQ * DIM;

    const size_t t_el = (size_t)BATCH * EL_B;              // 4,194,304
    const size_t need = 2 * t_el * 2;                      // 16.8 MB

    if (ws_size >= need) {
        _Float16* kh = (_Float16*)d_ws;
        _Float16* vh = kh + t_el;
        preconvert<<<4096, 256, 0, stream>>>(k, v, kh, vh);
        attn_main<<<BATCH * (SEQ / MTILE), 256, 0, stream>>>(q, kh, vh, ctx, att);
    } else {
        attn_fallback<<<BATCH * (SEQ / 64), 256, 0, stream>>>(q, k, v, ctx, att);
    }
}

// Round 11
// 304.930 us; speedup vs baseline: 1.6966x; 1.0150x over previous
//
#include <hip/hip_runtime.h>
#include <hip/hip_bf16.h>

typedef _Float16 half8 __attribute__((ext_vector_type(8)));
typedef _Float16 half4 __attribute__((ext_vector_type(4)));
typedef short short8 __attribute__((ext_vector_type(8)));
typedef short short4v __attribute__((ext_vector_type(4)));
typedef float f32x4 __attribute__((ext_vector_type(4)));

#define BATCH 16
#define SEQ   4096
#define DIM   64
#define MTILE 64              // q rows per workgroup (4 waves x 16)
#define KVB   64              // key chunk
#define NCH   (SEQ / KVB)     // 64 chunks
#define EL_CH 4096            // elems per chunk per tensor (512 frags * 8)
#define EL_B  (NCH * EL_CH)   // elems per batch per tensor (262144)

__device__ __forceinline__ short f2bf(float f) {
    unsigned u = __builtin_bit_cast(unsigned, f);
    u += 0x7FFF + ((u >> 16) & 1);          // round-to-nearest-even
    return (short)(u >> 16);
}
__device__ __forceinline__ float bf2f(short h) {
    return __builtin_bit_cast(float, (unsigned)((unsigned short)h) << 16);
}

__device__ __forceinline__ void gld16(const void* g, void* l) {
    __builtin_amdgcn_global_load_lds(
        (const __attribute__((address_space(1))) unsigned int*)g,
        (__attribute__((address_space(3))) unsigned int*)l, 16, 0, 0);
}

// ======== pre-kernel: K,V -> fp16 frag-linear (unchanged from r10) ========
// K frag(ch,nf,kk,lane) = K[ch*64 + nf*16 + (lane&15)][kk*32 + (lane>>4)*8 + e]
// V frag(ch,nf,kk,lane) = V[ch*64 + kk*32 + (lane>>4)*8 + e][nf*16 + (lane&15)]
__global__ __launch_bounds__(256) void preconvert(
    const float* __restrict__ k, const float* __restrict__ v,
    _Float16* __restrict__ kh, _Float16* __restrict__ vh)
{
    int f = blockIdx.x * 256 + threadIdx.x;   // 0 .. 2*524288-1
    int lane = f & 63;
    int sub  = (f >> 6) & 7;                  // nf*2 + kk
    int ch   = (f >> 9) & 63;
    int bb   = (f >> 15) & 15;
    int isV  = f >> 19;
    int nf = sub >> 1, kk = sub & 1;
    size_t fo = (size_t)(f & ((1 << 19) - 1)) * 8;

    if (!isV) {
        int key = ch * 64 + nf * 16 + (lane & 15);
        int d0  = kk * 32 + (lane >> 4) * 8;
        const float* src = k + (((size_t)bb * SEQ + key) * DIM + d0);
        half8 h8;
        #pragma unroll
        for (int e = 0; e < 8; ++e) h8[e] = (_Float16)src[e];
        *(half8*)(kh + fo) = h8;
    } else {
        int kr0 = kk * 32 + (lane >> 4) * 8;
        int d   = nf * 16 + (lane & 15);
        const float* src = v + (((size_t)bb * SEQ + ch * 64 + kr0) * DIM + d);
        half8 h8;
        #pragma unroll
        for (int e = 0; e < 8; ++e) h8[e] = (_Float16)src[e * DIM];
        *(half8*)(vh + fo) = h8;
    }
}

// ============================== main kernel ==============================
// Swapped QK^T: s = mfma(A=K_frag, B=Q_frag) -> D col=li=q, row=4h4+r=key.
// Each thread owns ONE q-row (q = li): softmax stats are scalar, P writes
// are 4x ds_write_b64 (4 consecutive keys each) instead of 16x ds_write_b16.
__global__ __launch_bounds__(256) void attn_main(
    const float* __restrict__ q, const _Float16* __restrict__ kh,
    const _Float16* __restrict__ vh, float* __restrict__ ctx,
    float* __restrict__ att)
{
    __shared__ _Float16 Kst[2][EL_CH];    // fp16 K chunk, double-buffered (16 KB)
    __shared__ _Float16 Vst[2][EL_CH];    // fp16 V^T chunk (16 KB)
    __shared__ _Float16 Ph[4][16][72];    // per-wave P fp16 [q][key] (9 KB)

    int id = blockIdx.x;                  // grid = 1024
    int bb = (id & 7) + 8 * (id >> 9);    // XCD-swizzled batch
    int qt = (id >> 3) & 63;

    int tid = threadIdx.x;
    int w = tid >> 6, lane = tid & 63, li = lane & 15, h4 = lane >> 4;

    // ---- Q B-fragments (fp16): this thread's q-row is qrow (q = li) ----
    int qrow = qt * MTILE + w * 16 + li;
    const float* qp = q + ((size_t)bb * SEQ + qrow) * DIM;
    half8 aq[2];
    #pragma unroll
    for (int kk = 0; kk < 2; ++kk)
        #pragma unroll
        for (int e = 0; e < 8; ++e)
            aq[kk][e] = (_Float16)qp[kk * 32 + h4 * 8 + e];

    const _Float16* khb = kh + (size_t)bb * EL_B;
    const _Float16* vvb = vh + (size_t)bb * EL_B;

    auto stage_k = [&](int buf, int ch) {
        const _Float16* g = khb + (size_t)ch * EL_CH + tid * 8;
        gld16(g,        &Kst[buf][w * 512]);
        gld16(g + 2048, &Kst[buf][2048 + w * 512]);
    };
    auto stage_v = [&](int buf, int ch) {
        const _Float16* g = vvb + (size_t)ch * EL_CH + tid * 8;
        gld16(g,        &Vst[buf][w * 512]);
        gld16(g + 2048, &Vst[buf][2048 + w * 512]);
    };
    // swapped QK^T: s[nf][r] = S[q=li][key = 16nf + 4h4 + r]
    auto qkt = [&](int buf, f32x4* s) {
        const half8* k8 = (const half8*)&Kst[buf][0];
        #pragma unroll
        for (int kk = 0; kk < 2; ++kk)
            #pragma unroll
            for (int nf = 0; nf < 4; ++nf)
                s[nf] = __builtin_amdgcn_mfma_f32_16x16x32_f16(
                    k8[(nf * 2 + kk) * 64 + lane], aq[kk], s[nf], 0, 0, 0);
    };

    // ========== pass 1: l = sum exp(s)  (max-free: |s| <~ 60, fp32 safe) ====
    float ll = 0.f;

    stage_k(0, 0);
    for (int ch = 0; ch < NCH; ++ch) {
        int buf = ch & 1;
        if (ch + 1 < NCH) {
            stage_k(buf ^ 1, ch + 1);
            asm volatile("s_waitcnt vmcnt(2)" ::: "memory");
        } else {
            asm volatile("s_waitcnt vmcnt(0)" ::: "memory");
        }
        __builtin_amdgcn_s_barrier();
        asm volatile("" ::: "memory");

        f32x4 s[4];
        #pragma unroll
        for (int nf = 0; nf < 4; ++nf) s[nf] = (f32x4){0.f, 0.f, 0.f, 0.f};
        qkt(buf, s);

        float a = 0.f;
        #pragma unroll
        for (int nf = 0; nf < 4; ++nf)
            #pragma unroll
            for (int r = 0; r < 4; ++r)
                a += __expf(s[nf][r]);
        ll += a;

        asm volatile("" ::: "memory");
        __builtin_amdgcn_s_barrier();
    }

    // reduce over the 4 lanes sharing this q-row (h4 group), invert
    ll += __shfl_xor(ll, 16);
    ll += __shfl_xor(ll, 32);
    float rl = 1.0f / ll;

    // ========== pass 2: p = exp(s)*rl; att stores (16-lane dense); PV fp16 ==
    f32x4 acc[4];
    #pragma unroll
    for (int nf = 0; nf < 4; ++nf) acc[nf] = (f32x4){0.f, 0.f, 0.f, 0.f};

    float* attb = att + ((size_t)bb * SEQ + (size_t)qt * MTILE + w * 16) * SEQ;

    stage_k(0, 0); stage_v(0, 0);
    for (int ch = 0; ch < NCH; ++ch) {
        int buf = ch & 1;
        if (ch + 1 < NCH) {
            stage_k(buf ^ 1, ch + 1);
            stage_v(buf ^ 1, ch + 1);
            // queue: [4 loads cur][4 stores prev][4 loads next]
            // vmcnt(8): cur loads retired; stores + next loads ride.
            if (ch == 0) asm volatile("s_waitcnt vmcnt(4)" ::: "memory");
            else         asm volatile("s_waitcnt vmcnt(8)" ::: "memory");
        } else {
            asm volatile("s_waitcnt vmcnt(4)" ::: "memory");
        }
        __builtin_amdgcn_s_barrier();
        asm volatile("" ::: "memory");

        f32x4 s[4];
        #pragma unroll
        for (int nf = 0; nf < 4; ++nf) s[nf] = (f32x4){0.f, 0.f, 0.f, 0.f};
        qkt(buf, s);

        // p -> Ph[q=li][key]: 4 consecutive keys per write -> ds_write_b64
        #pragma unroll
        for (int nf = 0; nf < 4; ++nf) {
            half4 p4;
            #pragma unroll
            for (int r = 0; r < 4; ++r)
                p4[r] = (_Float16)(__expf(s[nf][r]) * rl);
            *(half4*)&Ph[w][li][nf * 16 + h4 * 4] = p4;
        }

        // att stores, 16-lane contiguous (proven r10 pattern)
        #pragma unroll
        for (int j = 0; j < 4; ++j) {
            int row = j * 4 + h4;
            half4 ph = *(const half4*)&Ph[w][row][li * 4];
            f32x4 pv = { (float)ph[0], (float)ph[1], (float)ph[2], (float)ph[3] };
            __builtin_nontemporal_store(
                pv, (f32x4*)(attb + (size_t)row * SEQ + ch * KVB + li * 4));
        }

        // PV (fp16): acc[q][d] += P[q][key] * V[key][d]  (unchanged)
        const half8* v8 = (const half8*)&Vst[buf][0];
        #pragma unroll
        for (int kk = 0; kk < 2; ++kk) {
            half8 pa = *(const half8*)&Ph[w][li][kk * 32 + h4 * 8];
            #pragma unroll
            for (int nf = 0; nf < 4; ++nf)
                acc[nf] = __builtin_amdgcn_mfma_f32_16x16x32_f16(
                    pa, v8[(nf * 2 + kk) * 64 + lane], acc[nf], 0, 0, 0);
        }

        asm volatile("" ::: "memory");
        __builtin_amdgcn_s_barrier();
    }

    float* ctxb = ctx + ((size_t)bb * SEQ + (size_t)qt * MTILE + w * 16) * DIM;
    #pragma unroll
    for (int nf = 0; nf < 4; ++nf)
        #pragma unroll
        for (int r = 0; r < 4; ++r)
            __builtin_nontemporal_store(
                acc[nf][r], &ctxb[(size_t)(4 * h4 + r) * DIM + nf * 16 + li]);
}

// ===================== fallback (round-2 kernel, proven) =====================
__global__ __launch_bounds__(256) void attn_fallback(
    const float* __restrict__ q, const float* __restrict__ k,
    const float* __restrict__ v, float* __restrict__ ctx,
    float* __restrict__ att)
{
    __shared__ short K_hi[KVB][72];
    __shared__ short K_lo[KVB][72];
    __shared__ short V_lds[DIM][72];
    __shared__ short P_lds[4][16][72];

    int id = blockIdx.x;
    int bb = (id & 7) + 8 * (id >> 9);
    int qt = (id >> 3) & 63;
    int tid = threadIdx.x;
    int w = tid >> 6, lane = tid & 63, li = lane & 15, h4 = lane >> 4;

    int qrow = qt * 64 + w * 16 + li;
    const float* qp = q + ((size_t)bb * SEQ + qrow) * DIM;
    short8 aq[2], aql[2];
    #pragma unroll
    for (int kk = 0; kk < 2; ++kk)
        #pragma unroll
        for (int e = 0; e < 8; ++e) {
            float x = qp[kk * 32 + h4 * 8 + e];
            short h = f2bf(x);
            aq[kk][e] = h; aql[kk][e] = f2bf(x - bf2f(h));
        }

    float m[4], l[4];
    #pragma unroll
    for (int r = 0; r < 4; ++r) { m[r] = -3.0e38f; l[r] = 0.0f; }
    const float* kbase = k + (size_t)bb * SEQ * DIM;
    const float* vbase = v + (size_t)bb * SEQ * DIM;

    for (int ch = 0; ch < NCH; ++ch) {
        __syncthreads();
        const float4* kc = (const float4*)(kbase + (size_t)ch * KVB * DIM);
        #pragma unroll
        for (int j = 0; j < 4; ++j) {
            int f4 = j * 256 + tid; int key = f4 >> 4, d4 = f4 & 15;
            float4 val = kc[f4];
            short4v h4v, l4v;
            h4v[0]=f2bf(val.x); l4v[0]=f2bf(val.x-bf2f(h4v[0]));
            h4v[1]=f2bf(val.y); l4v[1]=f2bf(val.y-bf2f(h4v[1]));
            h4v[2]=f2bf(val.z); l4v[2]=f2bf(val.z-bf2f(h4v[2]));
            h4v[3]=f2bf(val.w); l4v[3]=f2bf(val.w-bf2f(h4v[3]));
            *(short4v*)&K_hi[key][d4*4] = h4v;
            *(short4v*)&K_lo[key][d4*4] = l4v;
        }
        __syncthreads();
        f32x4 s[4];
        #pragma unroll
        for (int nf = 0; nf < 4; ++nf) s[nf] = (f32x4){0.f,0.f,0.f,0.f};
        #pragma unroll
        for (int kk = 0; kk < 2; ++kk)
            #pragma unroll
            for (int nf = 0; nf < 4; ++nf) {
                short8 kbv = *(const short8*)&K_hi[nf*16+li][kk*32+h4*8];
                short8 klv = *(const short8*)&K_lo[nf*16+li][kk*32+h4*8];
                s[nf] = __builtin_amdgcn_mfma_f32_16x16x32_bf16(aq[kk],  kbv, s[nf],0,0,0);
                s[nf] = __builtin_amdgcn_mfma_f32_16x16x32_bf16(aq[kk],  klv, s[nf],0,0,0);
                s[nf] = __builtin_amdgcn_mfma_f32_16x16x32_bf16(aql[kk], kbv, s[nf],0,0,0);
            }
        #pragma unroll
        for (int r = 0; r < 4; ++r) {
            float cmax = fmaxf(fmaxf(s[0][r],s[1][r]), fmaxf(s[2][r],s[3][r]));
            #pragma unroll
            for (int off = 1; off < 16; off <<= 1) cmax = fmaxf(cmax, __shfl_xor(cmax, off));
            float mnew = fmaxf(m[r], cmax);
            float cs = __expf(s[0][r]-mnew)+__expf(s[1][r]-mnew)+__expf(s[2][r]-mnew)+__expf(s[3][r]-mnew);
            #pragma unroll
            for (int off = 1; off < 16; off <<= 1) cs += __shfl_xor(cs, off);
            l[r] = l[r]*__expf(m[r]-mnew) + cs; m[r] = mnew;
        }
    }
    float rl[4];
    #pragma unroll
    for (int r = 0; r < 4; ++r) rl[r] = 1.0f / l[r];

    f32x4 acc[4];
    #pragma unroll
    for (int nf = 0; nf < 4; ++nf) acc[nf] = (f32x4){0.f,0.f,0.f,0.f};
    float* attb = att + ((size_t)bb * SEQ + (size_t)qt * 64 + w * 16) * SEQ;

    for (int ch = 0; ch < NCH; ++ch) {
        __syncthreads();
        const float4* kc = (const float4*)(kbase + (size_t)ch * KVB * DIM);
        #pragma unroll
        for (int j = 0; j < 4; ++j) {
            int f4 = j * 256 + tid; int key = f4 >> 4, d4 = f4 & 15;
            float4 val = kc[f4];
            short4v h4v, l4v;
            h4v[0]=f2bf(val.x); l4v[0]=f2bf(val.x-bf2f(h4v[0]));
            h4v[1]=f2bf(val.y); l4v[1]=f2bf(val.y-bf2f(h4v[1]));
            h4v[2]=f2bf(val.z); l4v[2]=f2bf(val.z-bf2f(h4v[2]));
            h4v[3]=f2bf(val.w); l4v[3]=f2bf(val.w-bf2f(h4v[3]));
            *(short4v*)&K_hi[key][d4*4] = h4v;
            *(short4v*)&K_lo[key][d4*4] = l4v;
        }
        {
            int key = tid & 63, dblk = (tid >> 6) * 16;
            const float* vc = vbase + ((size_t)ch * KVB + key) * DIM + dblk;
            #pragma unroll
            for (int j = 0; j < 4; ++j) {
                float4 val = *(const float4*)(vc + j * 4);
                V_lds[dblk+j*4+0][key]=f2bf(val.x); V_lds[dblk+j*4+1][key]=f2bf(val.y);
                V_lds[dblk+j*4+2][key]=f2bf(val.z); V_lds[dblk+j*4+3][key]=f2bf(val.w);
            }
        }
        __syncthreads();
        f32x4 s[4];
        #pragma unroll
        for (int nf = 0; nf < 4; ++nf) s[nf] = (f32x4){0.f,0.f,0.f,0.f};
        #pragma unroll
        for (int kk = 0; kk < 2; ++kk)
            #pragma unroll
            for (int nf = 0; nf < 4; ++nf) {
                short8 kbv = *(const short8*)&K_hi[nf*16+li][kk*32+h4*8];
                short8 klv = *(const short8*)&K_lo[nf*16+li][kk*32+h4*8];
                s[nf] = __builtin_amdgcn_mfma_f32_16x16x32_bf16(aq[kk],  kbv, s[nf],0,0,0);
                s[nf] = __builtin_amdgcn_mfma_f32_16x16x32_bf16(aq[kk],  klv, s[nf],0,0,0);
                s[nf] = __builtin_amdgcn_mfma_f32_16x16x32_bf16(aql[kk], kbv, s[nf],0,0,0);
            }
        #pragma unroll
        for (int nf = 0; nf < 4; ++nf)
            #pragma unroll
            for (int r = 0; r < 4; ++r) {
                float p = __expf(s[nf][r] - m[r]) * rl[r];
                __builtin_nontemporal_store(p, &attb[(size_t)(4*h4+r)*SEQ + ch*KVB + nf*16 + li]);
                P_lds[w][4*h4+r][nf*16+li] = f2bf(p);
            }
        #pragma unroll
        for (int kk = 0; kk < 2; ++kk) {
            short8 pa = *(const short8*)&P_lds[w][li][kk*32+h4*8];
            #pragma unroll
            for (int nf = 0; nf < 4; ++nf) {
                short8 vbv = *(const short8*)&V_lds[nf*16+li][kk*32+h4*8];
                acc[nf] = __builtin_amdgcn_mfma_f32_16x16x32_bf16(pa, vbv, acc[nf],0,0,0);
            }
        }
    }
    float* ctxb = ctx + ((size_t)bb * SEQ + (size_t)qt * 64 + w * 16) * DIM;
    #pragma unroll
    for (int nf = 0; nf < 4; ++nf)
        #pragma unroll
        for (int r = 0; r < 4; ++r)
            __builtin_nontemporal_store(acc[nf][r], &ctxb[(size_t)(4*h4+r)*DIM + nf*16 + li]);
}

extern "C" void kernel_launch(void* const* d_in, const int* in_sizes, int n_in,
                              void* d_out, int out_size, void* d_ws, size_t ws_size,
                              hipStream_t stream) {
    const float* q = (const float*)d_in[0];
    const float* k = (const float*)d_in[1];
    const float* v = (const float*)d_in[2];
    float* ctx = (float*)d_out;
    float* att = (float*)d_out + (size_t)BATCH * SEQ * DIM;

    const size_t t_el = (size_t)BATCH * EL_B;              // 4,194,304
    const size_t need = 2 * t_el * 2;                      // 16.8 MB

    if (ws_size >= need) {
        _Float16* kh = (_Float16*)d_ws;
        _Float16* vh = kh + t_el;
        preconvert<<<4096, 256, 0, stream>>>(k, v, kh, vh);
        attn_main<<<BATCH * (SEQ / MTILE), 256, 0, stream>>>(q, kh, vh, ctx, att);
    } else {
        attn_fallback<<<BATCH * (SEQ / 64), 256, 0, stream>>>(q, k, v, ctx, att);
    }
}